// Round 1
// baseline (1799.599 us; speedup 1.0000x reference)
//
#include <hip/hip_runtime.h>
#include <hip/hip_bf16.h>

#define N_PTS 8192
#define NSAMP 1024
#define NGRP  32

typedef __attribute__((ext_vector_type(8))) short bf16x8;   // MFMA A/B frag
typedef __attribute__((ext_vector_type(4))) float f32x4;    // MFMA C/D frag

static __device__ inline unsigned short f2bf(float f) {
  __hip_bfloat16 h = __float2bfloat16(f);   // RTNE
  return __builtin_bit_cast(unsigned short, h);
}

// DPP max step: invalid lanes keep 'old' (=r), identity for max.
#define DPP_MAXSTEP(r, ctrl)                                                  \
  r = fmaxf(r, __int_as_float(__builtin_amdgcn_update_dpp(                    \
          __float_as_int(r), __float_as_int(r), (ctrl), 0xf, 0xf, false)))

// 8-slot cross-wave argmax from LDS (strict > keeps lowest wave on ties).
#define FINAL8(P, V, F) do {                                                  \
    const uint4* pp_ = (const uint4*)&(P)[0];                                 \
    uint4 p0_ = pp_[0], p1_ = pp_[1], p2_ = pp_[2], p3_ = pp_[3];             \
    V = __uint_as_float(p0_.x); F = p0_.y;                                    \
    float q_;                                                                 \
    q_ = __uint_as_float(p0_.z); if (q_ > V) { V = q_; F = p0_.w; }           \
    q_ = __uint_as_float(p1_.x); if (q_ > V) { V = q_; F = p1_.y; }           \
    q_ = __uint_as_float(p1_.z); if (q_ > V) { V = q_; F = p1_.w; }           \
    q_ = __uint_as_float(p2_.x); if (q_ > V) { V = q_; F = p2_.y; }           \
    q_ = __uint_as_float(p2_.z); if (q_ > V) { V = q_; F = p2_.w; }           \
    q_ = __uint_as_float(p3_.x); if (q_ > V) { V = q_; F = p3_.y; }           \
    q_ = __uint_as_float(p3_.z); if (q_ > V) { V = q_; F = p3_.w; }           \
  } while (0)

static __device__ inline void load16(const float* __restrict__ bx, int t,
                                     float px[16], float py[16], float pz[16]) {
  const float4* src = (const float4*)(bx + t * 48);
  float4 v0 = src[0], v1 = src[1], v2 = src[2];
  float4 v3 = src[3], v4 = src[4], v5 = src[5];
  float4 v6 = src[6], v7 = src[7], v8 = src[8];
  float4 v9 = src[9], v10 = src[10], v11 = src[11];
  px[ 0]=v0.x; py[ 0]=v0.y; pz[ 0]=v0.z;
  px[ 1]=v0.w; py[ 1]=v1.x; pz[ 1]=v1.y;
  px[ 2]=v1.z; py[ 2]=v1.w; pz[ 2]=v2.x;
  px[ 3]=v2.y; py[ 3]=v2.z; pz[ 3]=v2.w;
  px[ 4]=v3.x; py[ 4]=v3.y; pz[ 4]=v3.z;
  px[ 5]=v3.w; py[ 5]=v4.x; pz[ 5]=v4.y;
  px[ 6]=v4.z; py[ 6]=v4.w; pz[ 6]=v5.x;
  px[ 7]=v5.y; py[ 7]=v5.z; pz[ 7]=v5.w;
  px[ 8]=v6.x; py[ 8]=v6.y; pz[ 8]=v6.z;
  px[ 9]=v6.w; py[ 9]=v7.x; pz[ 9]=v7.y;
  px[10]=v7.z; py[10]=v7.w; pz[10]=v8.x;
  px[11]=v8.y; py[11]=v8.z; pz[11]=v8.w;
  px[12]=v9.x; py[12]=v9.y; pz[12]=v9.z;
  px[13]=v9.w; py[13]=v10.x; pz[13]=v10.y;
  px[14]=v10.z; py[14]=v10.w; pz[14]=v11.x;
  px[15]=v11.y; py[15]=v11.z; pz[15]=v11.w;
}

// ---------------------------------------------------------------------------
// Kernel 1: farthest point sampling — TWO BATCHES PER BLOCK (R11).
// R7-R10 established: one batch per block is lockstep-bound — ~800cy issue +
// ~1200cy serial latency per iteration that NO single dependency stream can
// hide. Fix: co-schedule a second, independent batch in the same block.
// Each thread owns 16 points of batch A and 16 of batch B, fully interleaved;
// while A's DPP chain / LDS reduce / dependent centroid load stalls, B's
// issue stream fills the SIMD. One shared barrier per iteration (amortized).
// Per-batch arithmetic, thread->point mapping, wave order and tie-break chain
// are IDENTICAL to R7 -> bit-exact same sampled points.
//   d = fma(dz,dz, fma(dy,dy, dx*dx))          (bit-exact, DO NOT TOUCH)
// argmax ties -> lowest index.
// ---------------------------------------------------------------------------
__global__
__attribute__((amdgpu_flat_work_group_size(512, 512)))
__attribute__((amdgpu_waves_per_eu(2, 2)))
void fps_kernel(
    const float* __restrict__ xyz, float* __restrict__ out_sampled)
{
  #pragma clang fp contract(off)
  const int b0 = blockIdx.x * 2;
  const int t  = threadIdx.x;
  const float* bxA = xyz + (size_t)b0 * N_PTS * 3;
  const float* bxB = xyz + (size_t)(b0 + 1) * N_PTS * 3;

  float pxA[16], pyA[16], pzA[16], dsA[16];
  float pxB[16], pyB[16], pzB[16], dsB[16];
  load16(bxA, t, pxA, pyA, pzA);
  load16(bxB, t, pxB, pyB, pzB);
  #pragma unroll
  for (int r = 0; r < 16; ++r) { dsA[r] = 10000000000.0f; dsB[r] = 10000000000.0f; }

  __shared__ __align__(16) uint2 part[2][2][8];   // [slot][batch][wave]
  __shared__ float out_lds[2][NSAMP * 3];         // centroids, flushed at end

  const int lane = t & 63;
  const int wv   = t >> 6;

  float cxA = bxA[0], cyA = bxA[1], czA = bxA[2];  // initial centroid = pt 0
  float cxB = bxB[0], cyB = bxB[1], czB = bxB[2];

  for (int it = 0; it < NSAMP; ++it) {
    if (t == 0) {
      out_lds[0][it * 3 + 0] = cxA;
      out_lds[0][it * 3 + 1] = cyA;
      out_lds[0][it * 3 + 2] = czA;
      out_lds[1][it * 3 + 0] = cxB;
      out_lds[1][it * 3 + 1] = cyB;
      out_lds[1][it * 3 + 2] = czB;
    }

    float bvA = -1.0f, bvB = -1.0f;
    #pragma unroll
    for (int r = 0; r < 16; ++r) {
      float dxA = pxA[r] - cxA, dyA = pyA[r] - cyA, dzA = pzA[r] - czA;
      float dxB = pxB[r] - cxB, dyB = pyB[r] - cyB, dzB = pzB[r] - czB;
      float dA  = fmaf(dzA, dzA, fmaf(dyA, dyA, dxA * dxA));  // scan-fused rounding
      float dB  = fmaf(dzB, dzB, fmaf(dyB, dyB, dxB * dxB));
      float ndA = fminf(dsA[r], dA);
      float ndB = fminf(dsB[r], dB);
      dsA[r] = ndA;            dsB[r] = ndB;
      bvA = fmaxf(bvA, ndA);   bvB = fmaxf(bvB, ndB);
    }
    int biA = t * 16 + 15, biB = t * 16 + 15;
    #pragma unroll
    for (int r = 14; r >= 0; --r) {
      biA = (dsA[r] == bvA) ? (t * 16 + r) : biA;
      biB = (dsB[r] == bvB) ? (t * 16 + r) : biB;
    }

    float rmA = bvA, rmB = bvB;
    DPP_MAXSTEP(rmA, 0x111); DPP_MAXSTEP(rmB, 0x111);  // row_shr:1
    DPP_MAXSTEP(rmA, 0x112); DPP_MAXSTEP(rmB, 0x112);  // row_shr:2
    DPP_MAXSTEP(rmA, 0x114); DPP_MAXSTEP(rmB, 0x114);  // row_shr:4
    DPP_MAXSTEP(rmA, 0x118); DPP_MAXSTEP(rmB, 0x118);  // row_shr:8
    DPP_MAXSTEP(rmA, 0x142); DPP_MAXSTEP(rmB, 0x142);  // row_bcast:15
    DPP_MAXSTEP(rmA, 0x143); DPP_MAXSTEP(rmB, 0x143);  // row_bcast:31
    float vmA = __int_as_float(
        __builtin_amdgcn_readlane(__float_as_int(rmA), 63));
    float vmB = __int_as_float(
        __builtin_amdgcn_readlane(__float_as_int(rmB), 63));

    unsigned long long mA = __ballot(bvA == vmA);
    unsigned long long mB = __ballot(bvB == vmB);
    int LA = __ffsll((long long)mA) - 1;
    int LB = __ffsll((long long)mB) - 1;
    int wiA = __builtin_amdgcn_readlane(biA, LA);
    int wiB = __builtin_amdgcn_readlane(biB, LB);

    const int slot = it & 1;
    if (lane == 0) {
      part[slot][0][wv] = make_uint2(__float_as_uint(vmA), (unsigned)wiA);
      part[slot][1][wv] = make_uint2(__float_as_uint(vmB), (unsigned)wiB);
    }
    __syncthreads();   // the ONLY barrier; ping-pong makes it WAR-safe

    float vA; unsigned fA;
    float vB; unsigned fB;
    FINAL8(part[slot][0], vA, fA);
    FINAL8(part[slot][1], vB, fB);

    cxA = bxA[fA * 3 + 0]; cyA = bxA[fA * 3 + 1]; czA = bxA[fA * 3 + 2];
    cxB = bxB[fB * 3 + 0]; cyB = bxB[fB * 3 + 1]; czB = bxB[fB * 3 + 2];
  }

  __syncthreads();
  float* obA = out_sampled + (size_t)b0 * NSAMP * 3;
  float* obB = obA + NSAMP * 3;
  for (int i = t; i < NSAMP * 3; i += 512) {
    obA[i] = out_lds[0][i];
    obB[i] = out_lds[1][i];
  }
}

// ---------------------------------------------------------------------------
// Kernel 2: query_ball_point — unchanged (bit-exact, DO NOT TOUCH).
// ---------------------------------------------------------------------------
__global__ __launch_bounds__(256) void ball_kernel(
    const float* __restrict__ xyz, const float* __restrict__ sampled,
    int* __restrict__ gidx)
{
  #pragma clang fp contract(off)
  const float R2 = (float)(0.2 * 0.2);
  int gt = blockIdx.x * 256 + threadIdx.x;
  int w = gt >> 6;
  int lane = gt & 63;
  const int b = w >> 10;
  const float* cp = sampled + (size_t)w * 3;
  float cx = cp[0], cy = cp[1], cz = cp[2];
  float na = ((cx * cx) + (cy * cy)) + (cz * cz);   // eager: plain adds
  const float* bx = xyz + (size_t)b * N_PTS * 3;
  int* out = gidx + (size_t)w * NGRP;

  int cnt = 0;
  int first = 0;
  for (int base = 0; base < N_PTS && cnt < NGRP; base += 64) {
    int p = base + lane;
    float x = bx[p * 3 + 0];
    float y = bx[p * 3 + 1];
    float z = bx[p * 3 + 2];
    float nb  = ((x * x) + (y * y)) + (z * z);      // eager: plain adds
    float dot = fmaf(cz, z, fmaf(cy, y, cx * x));   // Eigen fma chain
    float sq  = (na + nb) - (2.0f * dot);
    bool inr = !(sq > R2);
    unsigned long long m = __ballot(inr);
    if (cnt == 0 && m != 0ull) first = base + (__ffsll(m) - 1);
    int before = __popcll(m & ((1ull << lane) - 1ull));
    int pos = cnt + before;
    if (inr && pos < NGRP) out[pos] = p;
    cnt += __popcll(m);
  }
  if (cnt < NGRP) {
    int q = cnt + lane;
    if (q < NGRP) out[q] = first;
  }
}

// ---------------------------------------------------------------------------
// Kernel 2.5: weight prep — pack W1/W2/W3 into fragment-ordered bf16 records.
// Record (nt, ks) holds the B-fragment for one 16-col tile / one K-step:
//   record[lane][j] = W[k = 32ks + (lane>>4)*8 + j][n = 16nt + (lane&15)]
// (zero-padded k >= K). 1KB/record, lane*16B consecutive -> coalesced loads.
// Layers: L1 4nt x 3ks = 12 recs, L2 8x2 = 16, L3 16x4 = 64. Total 92KB.
// ---------------------------------------------------------------------------
__global__ __launch_bounds__(256) void prep_w_kernel(
    const float* __restrict__ W1, const float* __restrict__ W2,
    const float* __restrict__ W3, unsigned short* __restrict__ wf1,
    unsigned short* __restrict__ wf2, unsigned short* __restrict__ wf3)
{
  int tid = blockIdx.x * 256 + threadIdx.x;
  int rec = tid >> 6, lane = tid & 63;
  if (rec >= 92) return;
  const float* W; unsigned short* dst; int N, K, ksteps, rl;
  if (rec < 12)      { W = W1; dst = wf1; N = 64;  K = 67;  ksteps = 3; rl = rec; }
  else if (rec < 28) { W = W2; dst = wf2; N = 128; K = 64;  ksteps = 2; rl = rec - 12; }
  else               { W = W3; dst = wf3; N = 256; K = 128; ksteps = 4; rl = rec - 28; }
  int nt = rl / ksteps, ks = rl - nt * ksteps;
  int n  = nt * 16 + (lane & 15);
  int kb = ks * 32 + (lane >> 4) * 8;
  unsigned short v[8] __attribute__((aligned(16)));
  #pragma unroll
  for (int j = 0; j < 8; ++j) {
    int k = kb + j;
    v[j] = f2bf((k < K) ? W[k * N + n] : 0.0f);
  }
  *(uint4*)(dst + ((size_t)rl * 64 + lane) * 8) = *(const uint4*)v;
}

// ---------------------------------------------------------------------------
// Kernel 3: gather + MLP via bf16 MFMA (fp32 accumulate) + max-pool.
// One 256-thread block (4 waves) per centroid.
// Frag layouts (gfx950, HW-verified per guide):
//   A[m=lane&15][k=(lane>>4)*8+j]   B[n=lane&15][k=(lane>>4)*8+j]
//   C/D: col=lane&15, row=(lane>>4)*4+reg
// Activations in bf16 LDS tiles, row stride K+8 (breaks 128B bank pathology).
// B-frags load straight from fragment-ordered global records (L2-hot).
// Accuracy: bf16 operand rounding -> out err ~2-5e-3 << 2e-2 threshold.
// ---------------------------------------------------------------------------
__global__ __launch_bounds__(256, 4) void mlp_mfma_kernel(
    const float* __restrict__ xyz, const float* __restrict__ fea,
    const float* __restrict__ sampled, const int* __restrict__ gidx,
    const unsigned short* __restrict__ wf1, const unsigned short* __restrict__ wf2,
    const unsigned short* __restrict__ wf3, const float* __restrict__ b1,
    const float* __restrict__ b2, const float* __restrict__ b3,
    float* __restrict__ out)
{
  __shared__ __align__(16) unsigned short fT[32][104];  // feats bf16, K=96 pad
  __shared__ __align__(16) unsigned short h1[32][72];   // K=64 (+8 bank pad)
  __shared__ __align__(16) unsigned short h2[32][136];  // K=128 (+8 bank pad)
  __shared__ float pmax[8][256];
  __shared__ int   sidx[32];
  __shared__ float sc[4];

  const int bs = blockIdx.x;
  const int b  = bs >> 10;
  const int t  = threadIdx.x;
  const int w    = t >> 6;
  const int lane = t & 63;
  const int quad = lane >> 4;
  const int ncol = lane & 15;

  if (t < 32) sidx[t] = gidx[(size_t)bs * 32 + t];
  if (t < 3)  sc[t] = sampled[(size_t)bs * 3 + t];
  __syncthreads();

  // gather: rel(3) ++ fea(64) -> bf16 fT[pt][c], zero pad c in [67,96)
  {
    const int pt = t >> 3, c0 = t & 7;
    const int p = sidx[pt];
    const float* xp = xyz + ((size_t)b * N_PTS + p) * 3;
    const float* fp = fea + ((size_t)b * N_PTS + p) * 64;
    for (int c = c0; c < 96; c += 8) {
      float v = (c < 3) ? (xp[c] - sc[c]) : (c < 67 ? fp[c - 3] : 0.0f);
      fT[pt][c] = f2bf(v);
    }
  }
  __syncthreads();

  // layer 1: out [32 x 64]. 8 tiles (2m x 4n), 2/wave; K: 3 steps.
  #pragma unroll
  for (int q2 = 0; q2 < 2; ++q2) {
    const int tid = w * 2 + q2, mt = tid & 1, nt = tid >> 1;
    float bb = b1[nt * 16 + ncol];
    f32x4 acc = {bb, bb, bb, bb};
    #pragma unroll
    for (int ks = 0; ks < 3; ++ks) {
      bf16x8 a = *(const bf16x8*)&fT[mt * 16 + ncol][ks * 32 + quad * 8];
      bf16x8 bf = *(const bf16x8*)(wf1 + ((size_t)(nt * 3 + ks) * 64 + lane) * 8);
      acc = __builtin_amdgcn_mfma_f32_16x16x32_bf16(a, bf, acc, 0, 0, 0);
    }
    #pragma unroll
    for (int r = 0; r < 4; ++r)
      h1[mt * 16 + quad * 4 + r][nt * 16 + ncol] = f2bf(fmaxf(acc[r], 0.0f));
  }
  __syncthreads();

  // layer 2: out [32 x 128]. 16 tiles (2m x 8n), 4/wave; K: 2 steps.
  #pragma unroll
  for (int q2 = 0; q2 < 4; ++q2) {
    const int tid = w * 4 + q2, mt = tid & 1, nt = tid >> 1;
    float bb = b2[nt * 16 + ncol];
    f32x4 acc = {bb, bb, bb, bb};
    #pragma unroll
    for (int ks = 0; ks < 2; ++ks) {
      bf16x8 a = *(const bf16x8*)&h1[mt * 16 + ncol][ks * 32 + quad * 8];
      bf16x8 bf = *(const bf16x8*)(wf2 + ((size_t)(nt * 2 + ks) * 64 + lane) * 8);
      acc = __builtin_amdgcn_mfma_f32_16x16x32_bf16(a, bf, acc, 0, 0, 0);
    }
    #pragma unroll
    for (int r = 0; r < 4; ++r)
      h2[mt * 16 + quad * 4 + r][nt * 16 + ncol] = f2bf(fmaxf(acc[r], 0.0f));
  }
  __syncthreads();

  // layer 3 + pool: out [32 x 256]. 32 tiles (2m x 16n), 8/wave; K: 4 steps.
  #pragma unroll
  for (int q2 = 0; q2 < 8; ++q2) {
    const int tid = w * 8 + q2, mt = tid & 1, nt = tid >> 1;
    float bb = b3[nt * 16 + ncol];
    f32x4 acc = {bb, bb, bb, bb};
    #pragma unroll
    for (int ks = 0; ks < 4; ++ks) {
      bf16x8 a = *(const bf16x8*)&h2[mt * 16 + ncol][ks * 32 + quad * 8];
      bf16x8 bf = *(const bf16x8*)(wf3 + ((size_t)(nt * 4 + ks) * 64 + lane) * 8);
      acc = __builtin_amdgcn_mfma_f32_16x16x32_bf16(a, bf, acc, 0, 0, 0);
    }
    float mx = fmaxf(fmaxf(acc[0], acc[1]), fmaxf(acc[2], acc[3]));
    pmax[mt * 4 + quad][nt * 16 + ncol] = mx;   // partial over 4 rows
  }
  __syncthreads();

  {
    float v = pmax[0][t];
    #pragma unroll
    for (int s = 1; s < 8; ++s) v = fmaxf(v, pmax[s][t]);
    out[(size_t)bs * 256 + t] = fmaxf(v, 0.0f);   // relu(max) == max(relu)
  }
}

// ---------------------------------------------------------------------------
extern "C" void kernel_launch(void* const* d_in, const int* in_sizes, int n_in,
                              void* d_out, int out_size, void* d_ws, size_t ws_size,
                              hipStream_t stream) {
  const float* xyz = (const float*)d_in[0];
  const float* fea = (const float*)d_in[1];
  const float* W1  = (const float*)d_in[2];
  const float* b1  = (const float*)d_in[3];
  const float* W2  = (const float*)d_in[4];
  const float* b2  = (const float*)d_in[5];
  const float* W3  = (const float*)d_in[6];
  const float* b3  = (const float*)d_in[7];

  float* outp    = (float*)d_out;
  float* sampled = outp;                    // output 0: (16,1024,3)
  float* mlp_out = outp + 16 * 1024 * 3;    // output 1: (16,1024,256)
  int*   gidx    = (int*)d_ws;              // 2 MB
  unsigned short* wf1 = (unsigned short*)((char*)d_ws + (2u << 20));
  unsigned short* wf2 = wf1 + (size_t)12 * 64 * 8;   // 12 KB after wf1
  unsigned short* wf3 = wf2 + (size_t)16 * 64 * 8;   // 16 KB after wf2

  fps_kernel<<<8, 512, 0, stream>>>(xyz, sampled);
  prep_w_kernel<<<23, 256, 0, stream>>>(W1, W2, W3, wf1, wf2, wf3);
  ball_kernel<<<4096, 256, 0, stream>>>(xyz, sampled, gidx);
  mlp_mfma_kernel<<<16384, 256, 0, stream>>>(xyz, fea, sampled, gidx,
                                             wf1, wf2, wf3, b1, b2, b3, mlp_out);
}

// Round 2
// 1052.155 us; speedup vs baseline: 1.7104x; 1.7104x over previous
//
#include <hip/hip_runtime.h>
#include <hip/hip_bf16.h>

#define N_PTS 8192
#define NSAMP 1024
#define NGRP  32

typedef __attribute__((ext_vector_type(8))) short bf16x8;   // MFMA A/B frag
typedef __attribute__((ext_vector_type(4))) float f32x4;    // MFMA C/D frag
typedef __attribute__((ext_vector_type(2))) float f32x2;    // packed fp32 pair

static __device__ inline unsigned short f2bf(float f) {
  __hip_bfloat16 h = __float2bfloat16(f);   // RTNE
  return __builtin_bit_cast(unsigned short, h);
}

// DPP max step: invalid lanes keep 'old' (=r), identity for max.
#define DPP_MAXSTEP(r, ctrl)                                                  \
  r = fmaxf(r, __int_as_float(__builtin_amdgcn_update_dpp(                    \
          __float_as_int(r), __float_as_int(r), (ctrl), 0xf, 0xf, false)))

// 8-slot cross-wave argmax from LDS (strict > keeps lowest wave on ties).
#define FINAL8(P, V, F) do {                                                  \
    const uint4* pp_ = (const uint4*)&(P)[0];                                 \
    uint4 p0_ = pp_[0], p1_ = pp_[1], p2_ = pp_[2], p3_ = pp_[3];             \
    V = __uint_as_float(p0_.x); F = p0_.y;                                    \
    float q_;                                                                 \
    q_ = __uint_as_float(p0_.z); if (q_ > V) { V = q_; F = p0_.w; }           \
    q_ = __uint_as_float(p1_.x); if (q_ > V) { V = q_; F = p1_.y; }           \
    q_ = __uint_as_float(p1_.z); if (q_ > V) { V = q_; F = p1_.w; }           \
    q_ = __uint_as_float(p2_.x); if (q_ > V) { V = q_; F = p2_.y; }           \
    q_ = __uint_as_float(p2_.z); if (q_ > V) { V = q_; F = p2_.w; }           \
    q_ = __uint_as_float(p3_.x); if (q_ > V) { V = q_; F = p3_.y; }           \
    q_ = __uint_as_float(p3_.z); if (q_ > V) { V = q_; F = p3_.w; }           \
  } while (0)

static __device__ inline void load16(const float* __restrict__ bx, int t,
                                     float px[16], float py[16], float pz[16]) {
  const float4* src = (const float4*)(bx + t * 48);
  float4 v0 = src[0], v1 = src[1], v2 = src[2];
  float4 v3 = src[3], v4 = src[4], v5 = src[5];
  float4 v6 = src[6], v7 = src[7], v8 = src[8];
  float4 v9 = src[9], v10 = src[10], v11 = src[11];
  px[ 0]=v0.x; py[ 0]=v0.y; pz[ 0]=v0.z;
  px[ 1]=v0.w; py[ 1]=v1.x; pz[ 1]=v1.y;
  px[ 2]=v1.z; py[ 2]=v1.w; pz[ 2]=v2.x;
  px[ 3]=v2.y; py[ 3]=v2.z; pz[ 3]=v2.w;
  px[ 4]=v3.x; py[ 4]=v3.y; pz[ 4]=v3.z;
  px[ 5]=v3.w; py[ 5]=v4.x; pz[ 5]=v4.y;
  px[ 6]=v4.z; py[ 6]=v4.w; pz[ 6]=v5.x;
  px[ 7]=v5.y; py[ 7]=v5.z; pz[ 7]=v5.w;
  px[ 8]=v6.x; py[ 8]=v6.y; pz[ 8]=v6.z;
  px[ 9]=v6.w; py[ 9]=v7.x; pz[ 9]=v7.y;
  px[10]=v7.z; py[10]=v7.w; pz[10]=v8.x;
  px[11]=v8.y; py[11]=v8.z; pz[11]=v8.w;
  px[12]=v9.x; py[12]=v9.y; pz[12]=v9.z;
  px[13]=v9.w; py[13]=v10.x; pz[13]=v10.y;
  px[14]=v10.z; py[14]=v10.w; pz[14]=v11.x;
  px[15]=v11.y; py[15]=v11.z; pz[15]=v11.w;
}

// ---------------------------------------------------------------------------
// Kernel 1: farthest point sampling — R12.
// R11 post-mortem: batch-level TLP cannot cut wall time (16 idle-CU blocks);
// only the per-iteration critical path matters (~800cy issue + ~1200cy serial).
// R12 cuts both, bit-exact:
//  (a) packed fp32 (v_pk_fma/min/max) halves the distance-update issue
//      (128 -> 64 VALU/thread). Per-element IEEE ops identical to scalar.
//  (b) centroid re-read served from an LDS point table (broadcast ds_read,
//      ~120cy) instead of a random-index global L2 hit (~200cy + vmcnt drain).
// Distance rounding matches XLA:CPU's scan-compiled contracted reduce:
//   d = fma(dz,dz, fma(dy,dy, dx*dx))          (bit-exact, DO NOT TOUCH)
// argmax ties -> lowest index.
// ---------------------------------------------------------------------------
__global__
__attribute__((amdgpu_flat_work_group_size(512, 512)))
__attribute__((amdgpu_waves_per_eu(2, 2)))
void fps_kernel(
    const float* __restrict__ xyz, float* __restrict__ out_sampled)
{
  #pragma clang fp contract(off)
  const int b = blockIdx.x;
  const int t = threadIdx.x;
  const float* bx = xyz + (size_t)b * N_PTS * 3;

  float px[16], py[16], pz[16];
  load16(bx, t, px, py, pz);

  f32x2 px2[8], py2[8], pz2[8], ds2[8];
  #pragma unroll
  for (int j = 0; j < 8; ++j) {
    px2[j] = (f32x2){px[2*j], px[2*j+1]};
    py2[j] = (f32x2){py[2*j], py[2*j+1]};
    pz2[j] = (f32x2){pz[2*j], pz[2*j+1]};
    ds2[j] = (f32x2){10000000000.0f, 10000000000.0f};
  }

  __shared__ float lds_p[N_PTS * 3];    // full point table (96 KB): centroid
  __shared__ float out_lds[NSAMP * 3];  // centroids, flushed at end
  __shared__ __align__(16) uint2 part[2][8];  // ping-pong (value bits, index)

  // one-time coalesced stage of the point table (visible at first barrier)
  for (int i = t; i < N_PTS * 3; i += 512) lds_p[i] = bx[i];

  const int lane = t & 63;
  const int wv   = t >> 6;

  float cx = bx[0], cy = bx[1], cz = bx[2];  // initial centroid = point 0

  for (int it = 0; it < NSAMP; ++it) {
    if (t == 0) {
      out_lds[it * 3 + 0] = cx;
      out_lds[it * 3 + 1] = cy;
      out_lds[it * 3 + 2] = cz;
    }

    const f32x2 c2x = (f32x2){cx, cx};
    const f32x2 c2y = (f32x2){cy, cy};
    const f32x2 c2z = (f32x2){cz, cz};
    f32x2 bv2 = (f32x2){-1.0f, -1.0f};
    #pragma unroll
    for (int j = 0; j < 8; ++j) {
      f32x2 dx = px2[j] - c2x;
      f32x2 dy = py2[j] - c2y;
      f32x2 dz = pz2[j] - c2z;
      f32x2 d  = __builtin_elementwise_fma(
          dz, dz, __builtin_elementwise_fma(dy, dy, dx * dx));  // scan-fused
      f32x2 nd = __builtin_elementwise_min(ds2[j], d);
      ds2[j] = nd;
      bv2 = __builtin_elementwise_max(bv2, nd);
    }
    float bv = fmaxf(bv2.x, bv2.y);   // min/max reassociation is exact

    int bi = t * 16 + 15;
    #pragma unroll
    for (int r = 14; r >= 0; --r) {
      float dr = (r & 1) ? ds2[r >> 1].y : ds2[r >> 1].x;
      bi = (dr == bv) ? (t * 16 + r) : bi;
    }

    float rmax = bv;
    DPP_MAXSTEP(rmax, 0x111);  // row_shr:1
    DPP_MAXSTEP(rmax, 0x112);  // row_shr:2
    DPP_MAXSTEP(rmax, 0x114);  // row_shr:4
    DPP_MAXSTEP(rmax, 0x118);  // row_shr:8
    DPP_MAXSTEP(rmax, 0x142);  // row_bcast:15
    DPP_MAXSTEP(rmax, 0x143);  // row_bcast:31
    float vmax = __int_as_float(
        __builtin_amdgcn_readlane(__float_as_int(rmax), 63));

    unsigned long long m = __ballot(bv == vmax);
    int L = __ffsll((long long)m) - 1;
    int widx = __builtin_amdgcn_readlane(bi, L);

    const int slot = it & 1;
    if (lane == 0) part[slot][wv] = make_uint2(__float_as_uint(vmax), (unsigned)widx);
    __syncthreads();   // the ONLY barrier; ping-pong makes it WAR-safe

    float v; unsigned f;
    FINAL8(part[slot], v, f);

    cx = lds_p[f * 3 + 0];   // broadcast ds_read, ~120cy (was global L2 ~200cy)
    cy = lds_p[f * 3 + 1];
    cz = lds_p[f * 3 + 2];
  }

  __syncthreads();
  float* ob = out_sampled + (size_t)b * NSAMP * 3;
  for (int i = t; i < NSAMP * 3; i += 512) ob[i] = out_lds[i];
}

// ---------------------------------------------------------------------------
// Kernel 2: query_ball_point — unchanged (bit-exact, DO NOT TOUCH).
// ---------------------------------------------------------------------------
__global__ __launch_bounds__(256) void ball_kernel(
    const float* __restrict__ xyz, const float* __restrict__ sampled,
    int* __restrict__ gidx)
{
  #pragma clang fp contract(off)
  const float R2 = (float)(0.2 * 0.2);
  int gt = blockIdx.x * 256 + threadIdx.x;
  int w = gt >> 6;
  int lane = gt & 63;
  const int b = w >> 10;
  const float* cp = sampled + (size_t)w * 3;
  float cx = cp[0], cy = cp[1], cz = cp[2];
  float na = ((cx * cx) + (cy * cy)) + (cz * cz);   // eager: plain adds
  const float* bx = xyz + (size_t)b * N_PTS * 3;
  int* out = gidx + (size_t)w * NGRP;

  int cnt = 0;
  int first = 0;
  for (int base = 0; base < N_PTS && cnt < NGRP; base += 64) {
    int p = base + lane;
    float x = bx[p * 3 + 0];
    float y = bx[p * 3 + 1];
    float z = bx[p * 3 + 2];
    float nb  = ((x * x) + (y * y)) + (z * z);      // eager: plain adds
    float dot = fmaf(cz, z, fmaf(cy, y, cx * x));   // Eigen fma chain
    float sq  = (na + nb) - (2.0f * dot);
    bool inr = !(sq > R2);
    unsigned long long m = __ballot(inr);
    if (cnt == 0 && m != 0ull) first = base + (__ffsll(m) - 1);
    int before = __popcll(m & ((1ull << lane) - 1ull));
    int pos = cnt + before;
    if (inr && pos < NGRP) out[pos] = p;
    cnt += __popcll(m);
  }
  if (cnt < NGRP) {
    int q = cnt + lane;
    if (q < NGRP) out[q] = first;
  }
}

// ---------------------------------------------------------------------------
// Kernel 2.5: weight prep — pack W1/W2/W3 into fragment-ordered bf16 records.
// Record (nt, ks) holds the B-fragment for one 16-col tile / one K-step:
//   record[lane][j] = W[k = 32ks + (lane>>4)*8 + j][n = 16nt + (lane&15)]
// (zero-padded k >= K). 1KB/record, lane*16B consecutive -> coalesced loads.
// Layers: L1 4nt x 3ks = 12 recs, L2 8x2 = 16, L3 16x4 = 64. Total 92KB.
// ---------------------------------------------------------------------------
__global__ __launch_bounds__(256) void prep_w_kernel(
    const float* __restrict__ W1, const float* __restrict__ W2,
    const float* __restrict__ W3, unsigned short* __restrict__ wf1,
    unsigned short* __restrict__ wf2, unsigned short* __restrict__ wf3)
{
  int tid = blockIdx.x * 256 + threadIdx.x;
  int rec = tid >> 6, lane = tid & 63;
  if (rec >= 92) return;
  const float* W; unsigned short* dst; int N, K, ksteps, rl;
  if (rec < 12)      { W = W1; dst = wf1; N = 64;  K = 67;  ksteps = 3; rl = rec; }
  else if (rec < 28) { W = W2; dst = wf2; N = 128; K = 64;  ksteps = 2; rl = rec - 12; }
  else               { W = W3; dst = wf3; N = 256; K = 128; ksteps = 4; rl = rec - 28; }
  int nt = rl / ksteps, ks = rl - nt * ksteps;
  int n  = nt * 16 + (lane & 15);
  int kb = ks * 32 + (lane >> 4) * 8;
  unsigned short v[8] __attribute__((aligned(16)));
  #pragma unroll
  for (int j = 0; j < 8; ++j) {
    int k = kb + j;
    v[j] = f2bf((k < K) ? W[k * N + n] : 0.0f);
  }
  *(uint4*)(dst + ((size_t)rl * 64 + lane) * 8) = *(const uint4*)v;
}

// ---------------------------------------------------------------------------
// Kernel 3: gather + MLP via bf16 MFMA (fp32 accumulate) + max-pool.
// One 256-thread block (4 waves) per centroid.
// Frag layouts (gfx950, HW-verified per guide):
//   A[m=lane&15][k=(lane>>4)*8+j]   B[n=lane&15][k=(lane>>4)*8+j]
//   C/D: col=lane&15, row=(lane>>4)*4+reg
// Activations in bf16 LDS tiles, row stride K+8 (breaks 128B bank pathology).
// B-frags load straight from fragment-ordered global records (L2-hot).
// Accuracy: bf16 operand rounding -> out err ~2-5e-3 << 2e-2 threshold.
// ---------------------------------------------------------------------------
__global__ __launch_bounds__(256, 4) void mlp_mfma_kernel(
    const float* __restrict__ xyz, const float* __restrict__ fea,
    const float* __restrict__ sampled, const int* __restrict__ gidx,
    const unsigned short* __restrict__ wf1, const unsigned short* __restrict__ wf2,
    const unsigned short* __restrict__ wf3, const float* __restrict__ b1,
    const float* __restrict__ b2, const float* __restrict__ b3,
    float* __restrict__ out)
{
  __shared__ __align__(16) unsigned short fT[32][104];  // feats bf16, K=96 pad
  __shared__ __align__(16) unsigned short h1[32][72];   // K=64 (+8 bank pad)
  __shared__ __align__(16) unsigned short h2[32][136];  // K=128 (+8 bank pad)
  __shared__ float pmax[8][256];
  __shared__ int   sidx[32];
  __shared__ float sc[4];

  const int bs = blockIdx.x;
  const int b  = bs >> 10;
  const int t  = threadIdx.x;
  const int w    = t >> 6;
  const int lane = t & 63;
  const int quad = lane >> 4;
  const int ncol = lane & 15;

  if (t < 32) sidx[t] = gidx[(size_t)bs * 32 + t];
  if (t < 3)  sc[t] = sampled[(size_t)bs * 3 + t];
  __syncthreads();

  // gather: rel(3) ++ fea(64) -> bf16 fT[pt][c], zero pad c in [67,96)
  {
    const int pt = t >> 3, c0 = t & 7;
    const int p = sidx[pt];
    const float* xp = xyz + ((size_t)b * N_PTS + p) * 3;
    const float* fp = fea + ((size_t)b * N_PTS + p) * 64;
    for (int c = c0; c < 96; c += 8) {
      float v = (c < 3) ? (xp[c] - sc[c]) : (c < 67 ? fp[c - 3] : 0.0f);
      fT[pt][c] = f2bf(v);
    }
  }
  __syncthreads();

  // layer 1: out [32 x 64]. 8 tiles (2m x 4n), 2/wave; K: 3 steps.
  #pragma unroll
  for (int q2 = 0; q2 < 2; ++q2) {
    const int tid = w * 2 + q2, mt = tid & 1, nt = tid >> 1;
    float bb = b1[nt * 16 + ncol];
    f32x4 acc = {bb, bb, bb, bb};
    #pragma unroll
    for (int ks = 0; ks < 3; ++ks) {
      bf16x8 a = *(const bf16x8*)&fT[mt * 16 + ncol][ks * 32 + quad * 8];
      bf16x8 bf = *(const bf16x8*)(wf1 + ((size_t)(nt * 3 + ks) * 64 + lane) * 8);
      acc = __builtin_amdgcn_mfma_f32_16x16x32_bf16(a, bf, acc, 0, 0, 0);
    }
    #pragma unroll
    for (int r = 0; r < 4; ++r)
      h1[mt * 16 + quad * 4 + r][nt * 16 + ncol] = f2bf(fmaxf(acc[r], 0.0f));
  }
  __syncthreads();

  // layer 2: out [32 x 128]. 16 tiles (2m x 8n), 4/wave; K: 2 steps.
  #pragma unroll
  for (int q2 = 0; q2 < 4; ++q2) {
    const int tid = w * 4 + q2, mt = tid & 1, nt = tid >> 1;
    float bb = b2[nt * 16 + ncol];
    f32x4 acc = {bb, bb, bb, bb};
    #pragma unroll
    for (int ks = 0; ks < 2; ++ks) {
      bf16x8 a = *(const bf16x8*)&h1[mt * 16 + ncol][ks * 32 + quad * 8];
      bf16x8 bf = *(const bf16x8*)(wf2 + ((size_t)(nt * 2 + ks) * 64 + lane) * 8);
      acc = __builtin_amdgcn_mfma_f32_16x16x32_bf16(a, bf, acc, 0, 0, 0);
    }
    #pragma unroll
    for (int r = 0; r < 4; ++r)
      h2[mt * 16 + quad * 4 + r][nt * 16 + ncol] = f2bf(fmaxf(acc[r], 0.0f));
  }
  __syncthreads();

  // layer 3 + pool: out [32 x 256]. 32 tiles (2m x 16n), 8/wave; K: 4 steps.
  #pragma unroll
  for (int q2 = 0; q2 < 8; ++q2) {
    const int tid = w * 8 + q2, mt = tid & 1, nt = tid >> 1;
    float bb = b3[nt * 16 + ncol];
    f32x4 acc = {bb, bb, bb, bb};
    #pragma unroll
    for (int ks = 0; ks < 4; ++ks) {
      bf16x8 a = *(const bf16x8*)&h2[mt * 16 + ncol][ks * 32 + quad * 8];
      bf16x8 bf = *(const bf16x8*)(wf3 + ((size_t)(nt * 4 + ks) * 64 + lane) * 8);
      acc = __builtin_amdgcn_mfma_f32_16x16x32_bf16(a, bf, acc, 0, 0, 0);
    }
    float mx = fmaxf(fmaxf(acc[0], acc[1]), fmaxf(acc[2], acc[3]));
    pmax[mt * 4 + quad][nt * 16 + ncol] = mx;   // partial over 4 rows
  }
  __syncthreads();

  {
    float v = pmax[0][t];
    #pragma unroll
    for (int s = 1; s < 8; ++s) v = fmaxf(v, pmax[s][t]);
    out[(size_t)bs * 256 + t] = fmaxf(v, 0.0f);   // relu(max) == max(relu)
  }
}

// ---------------------------------------------------------------------------
extern "C" void kernel_launch(void* const* d_in, const int* in_sizes, int n_in,
                              void* d_out, int out_size, void* d_ws, size_t ws_size,
                              hipStream_t stream) {
  const float* xyz = (const float*)d_in[0];
  const float* fea = (const float*)d_in[1];
  const float* W1  = (const float*)d_in[2];
  const float* b1  = (const float*)d_in[3];
  const float* W2  = (const float*)d_in[4];
  const float* b2  = (const float*)d_in[5];
  const float* W3  = (const float*)d_in[6];
  const float* b3  = (const float*)d_in[7];

  float* outp    = (float*)d_out;
  float* sampled = outp;                    // output 0: (16,1024,3)
  float* mlp_out = outp + 16 * 1024 * 3;    // output 1: (16,1024,256)
  int*   gidx    = (int*)d_ws;              // 2 MB
  unsigned short* wf1 = (unsigned short*)((char*)d_ws + (2u << 20));
  unsigned short* wf2 = wf1 + (size_t)12 * 64 * 8;   // 12 KB after wf1
  unsigned short* wf3 = wf2 + (size_t)16 * 64 * 8;   // 16 KB after wf2

  fps_kernel<<<16, 512, 0, stream>>>(xyz, sampled);
  prep_w_kernel<<<23, 256, 0, stream>>>(W1, W2, W3, wf1, wf2, wf3);
  ball_kernel<<<4096, 256, 0, stream>>>(xyz, sampled, gidx);
  mlp_mfma_kernel<<<16384, 256, 0, stream>>>(xyz, fea, sampled, gidx,
                                             wf1, wf2, wf3, b1, b2, b3, mlp_out);
}